// Round 3
// baseline (533.720 us; speedup 1.0000x reference)
//
#include <hip/hip_runtime.h>

typedef __attribute__((ext_vector_type(8))) short short8;
typedef __attribute__((ext_vector_type(4))) float floatx4;

__device__ __forceinline__ unsigned short bf16_rne(float f) {
  unsigned int u = __builtin_bit_cast(unsigned int, f);
  u += 0x7fffu + ((u >> 16) & 1u);
  return (unsigned short)(u >> 16);
}

__device__ __forceinline__ void glds16(const void* g, void* l) {
  __builtin_amdgcn_global_load_lds((const __attribute__((address_space(1))) void*)g,
                                   (__attribute__((address_space(3))) void*)l, 16, 0, 0);
}

// xpad layout: [b][kc 8][pos 3364 = 58*58][cil 32] bf16  (chunk-major, glds-contiguous)
// agg  layout: [b][kc 8][rs 9][co 256][cil 32] bf16      (A-slab glds-contiguous)

// ---------------- zero pooled (32x256 floats) ----------------
__global__ __launch_bounds__(256) void zero_pooled_kernel(float* __restrict__ pooled) {
  pooled[blockIdx.x * 256 + threadIdx.x] = 0.f;
}

// ---------------- prep: transpose+cast x into xpad, fused pooled-sum ----------------
__global__ __launch_bounds__(256) void prep_kernel(const float* __restrict__ x,
                                                   unsigned short* __restrict__ xpad,
                                                   float* __restrict__ pooled) {
  const int bid = blockIdx.x;          // 32 b x 4 cig x 49 spc
  const int b   = bid / 196;
  const int rem = bid - b * 196;
  const int cig = rem / 49;
  const int spc = rem - cig * 49;
  const int t  = threadIdx.x;
  const int cs = t >> 6, sl = t & 63;
  const int sp0 = spc * 64;

  __shared__ float T[64][65];

  #pragma unroll
  for (int i = 0; i < 16; ++i) {
    const int cil = cs * 16 + i;
    T[cil][sl] = x[(size_t)(b * 256 + cig * 64 + cil) * 3136 + sp0 + sl];
  }
  __syncthreads();

  { // pooled partial sum: 4 threads per ci, 16 spatial each, banks 2-way only
    const int ci = t >> 2, g = t & 3;
    float s = 0.f;
    #pragma unroll
    for (int j = 0; j < 16; ++j) s += T[ci][g * 16 + j];
    atomicAdd(&pooled[b * 256 + cig * 64 + ci], s);
  }
  { // xpad write: short8 per thread, 64B segments
    unsigned short* xb = xpad + (size_t)b * (8 * 3364 * 32);
    const int oct = t & 7;
    const int cg8 = cig * 8 + oct;
    const int kc = cg8 >> 2, o2 = cg8 & 3;
    #pragma unroll
    for (int it = 0; it < 2; ++it) {
      const int spl = (t >> 3) + it * 32;
      const int spg = sp0 + spl;
      const int h = spg / 56, wc = spg - h * 56;
      const int pos = (h + 1) * 58 + (wc + 1);
      short8 v;
      #pragma unroll
      for (int jj = 0; jj < 8; ++jj) v[jj] = (short)bf16_rne(T[oct * 8 + jj][spl]);
      *(short8*)(xb + (size_t)kc * (3364 * 32) + pos * 32 + o2 * 8) = v;
    }
  }
}

// ---------------- zero the padding border of xpad ----------------
__global__ __launch_bounds__(256) void border_kernel(unsigned short* __restrict__ xpad) {
  const int b = blockIdx.x, quarter = blockIdx.y, t = threadIdx.x;
  const short8 z = {0, 0, 0, 0, 0, 0, 0, 0};
  unsigned short* xb = xpad + (size_t)b * (8 * 3364 * 32);
  for (int it = 0; it < 8; ++it) {
    const int idx = it * 256 + t;                 // 57 pos x 8 kc x 4 chunks = 1824
    if (idx >= 1824) break;
    const int s8 = idx & 3, kc = (idx >> 2) & 7, j = idx >> 5;
    const int pi = quarter * 57 + j;
    int h2, w2;
    if (pi < 58)       { h2 = 0;  w2 = pi; }
    else if (pi < 116) { h2 = 57; w2 = pi - 58; }
    else { const int k = pi - 116; h2 = 1 + (k >> 1); w2 = (k & 1) * 57; }
    *(short8*)(xb + (size_t)kc * (3364 * 32) + (h2 * 58 + w2) * 32 + s8 * 8) = z;
  }
}

// ---------------- att[b][k] = sigmoid(mean . att_w[k]) (pooled holds SUM) ----------------
__global__ void att_kernel(const float* __restrict__ pooled,
                           const float* __restrict__ att_w,
                           float* __restrict__ att) {
  const int t = threadIdx.x;               // 128: b = t>>2, k = t&3
  const int b = t >> 2, k = t & 3;
  float z = 0.f;
  for (int ci = 0; ci < 256; ++ci)
    z += pooled[b * 256 + ci] * att_w[k * 256 + ci];
  z *= (1.f / 3136.f);
  att[t] = 1.f / (1.f + expf(-z));
}

// ---------------- agg: one block per co; coalesced weight staging; new layout out ----------------
__global__ __launch_bounds__(256) void agg_kernel(const float* __restrict__ w,
                                                  const float* __restrict__ att,
                                                  unsigned short* __restrict__ agg) {
  const int co = blockIdx.x;
  const int t = threadIdx.x;
  __shared__ float W[4][2304];
  __shared__ float attl[128];
  if (t < 128) attl[t] = att[t];
  #pragma unroll
  for (int e = 0; e < 4; ++e) {
    const float* src = w + (size_t)(e * 256 + co) * 2304;
    #pragma unroll
    for (int j = 0; j < 9; ++j) W[e][j * 256 + t] = src[j * 256 + t];
  }
  __syncthreads();

  int widx[9], off9[9];
  #pragma unroll
  for (int j = 0; j < 9; ++j) {
    const int task = j * 256 + t;            // (kc,rs,cil)
    const int cil = task & 31, pair = task >> 5;
    const int kc = pair / 9, rs = pair - kc * 9;
    widx[j] = (kc * 32 + cil) * 9 + rs;      // w index: ci*9 + rs
    off9[j] = pair * 8192 + co * 32 + cil;   // agg offset within b
  }
  for (int b = 0; b < 32; ++b) {
    const float a0 = attl[b * 4 + 0], a1 = attl[b * 4 + 1];
    const float a2 = attl[b * 4 + 2], a3 = attl[b * 4 + 3];
    unsigned short* dst = agg + (size_t)b * 589824;
    #pragma unroll
    for (int j = 0; j < 9; ++j) {
      const int wi = widx[j];
      float s = a0 * W[0][wi] + a1 * W[1][wi] + a2 * W[2][wi] + a3 * W[3][wi];
      dst[off9[j]] = bf16_rne(s);
    }
  }
}

// ---------------- conv: implicit GEMM, 128co x 128p, 3-rs groups, 48 MFMA/barrier window ----------------
__global__ __launch_bounds__(256) void conv_kernel(const unsigned short* __restrict__ xpad,
                                                   const unsigned short* __restrict__ aggw,
                                                   float* __restrict__ out) {
  __shared__ unsigned short Bsm[348 * 32];       // 22272 B: [local pos][cil 32]
  __shared__ unsigned short Asm[3 * 128 * 32];   // 24576 B: [rsl][co 128][k 32]

  const int t  = threadIdx.x;
  const int bx = blockIdx.x;
  const int p_t  = bx % 25;
  const int co_t = (bx / 25) & 1;
  const int b    = bx / 50;
  const int p0   = p_t * 128;
  const int oh_min = p0 / 56;

  const unsigned short* xb  = xpad + (size_t)b * (8 * 3364 * 32);
  const unsigned short* awb = aggw + (size_t)b * 589824 + co_t * 4096;

  const int lane = t & 63;
  const int wv = t >> 6;
  const int wm = wv >> 1;                   // co half
  const int wn = wv & 1;                    // p half
  const int m16 = lane & 15;
  const int q = lane >> 4;

  int aoff[4], boff[4];
  #pragma unroll
  for (int i = 0; i < 4; ++i)
    aoff[i] = (wm * 64 + i * 16 + m16) * 32 + q * 8;
  #pragma unroll
  for (int j = 0; j < 4; ++j) {
    const int pf = p0 + wn * 64 + j * 16 + m16;
    const int oh = pf / 56;
    const int ow = pf - oh * 56;
    boff[j] = ((oh - oh_min) * 58 + ow) * 32 + q * 8;
  }

  floatx4 acc[4][4];
  #pragma unroll
  for (int i = 0; i < 4; ++i)
    #pragma unroll
    for (int j = 0; j < 4; ++j)
      acc[i][j] = (floatx4){0.f, 0.f, 0.f, 0.f};

  for (int kc = 0; kc < 8; ++kc) {
    const unsigned short* xkc = xb + (size_t)kc * (3364 * 32);
    // ---- stage B x-tile: 348 pos x 32 ci, contiguous 1KB glds ----
    #pragma unroll
    for (int i = 0; i < 6; ++i) {
      const int c = i * 256 + t;
      if (c < 1392) {
        const int pos = c >> 2, sub = c & 3;
        const int prow = pos / 58;
        const int pcol = pos - prow * 58;
        int ih2 = oh_min + prow; if (ih2 > 57) ih2 = 57;   // clamp (dup rows unused)
        glds16(xkc + ((size_t)(ih2 * 58 + pcol) * 32 + sub * 8), (void*)(Bsm + c * 8));
      }
    }
    #pragma unroll
    for (int g = 0; g < 3; ++g) {
      // ---- stage A: 3 rs-slices (r = g, s = 0..2), contiguous per slice ----
      #pragma unroll
      for (int i = 0; i < 6; ++i) {
        const int c = i * 256 + t;
        const int rsl = c >> 9;
        const int w5 = c & 511;
        glds16(awb + (size_t)(kc * 9 + g * 3 + rsl) * 8192 + w5 * 8, (void*)(Asm + c * 8));
      }
      __syncthreads();   // drains glds + barrier

      #pragma unroll
      for (int rsl = 0; rsl < 3; ++rsl) {
        const int d = (g * 58 + rsl) * 32;     // shift: r = g, s = rsl
        short8 af[4], bf[4];
        #pragma unroll
        for (int i = 0; i < 4; ++i)
          af[i] = *(const short8*)(Asm + rsl * 4096 + aoff[i]);
        #pragma unroll
        for (int j = 0; j < 4; ++j)
          bf[j] = *(const short8*)(Bsm + boff[j] + d);
        #pragma unroll
        for (int i = 0; i < 4; ++i)
          #pragma unroll
          for (int j = 0; j < 4; ++j)
            acc[i][j] = __builtin_amdgcn_mfma_f32_16x16x32_bf16(af[i], bf[j], acc[i][j], 0, 0, 0);
      }
      __syncthreads();   // protect Asm (and Bsm at kc rollover)
    }
  }

  // ---- epilogue: D col = lane&15 (p), row = q*4+reg (co) ----
  #pragma unroll
  for (int i = 0; i < 4; ++i) {
    const int co = co_t * 128 + wm * 64 + i * 16 + q * 4;
    float* orow = out + (size_t)(b * 256 + co) * 3136;
    #pragma unroll
    for (int j = 0; j < 4; ++j) {
      const int pp = p0 + wn * 64 + j * 16 + m16;
      if (pp < 3136) {
        #pragma unroll
        for (int rg = 0; rg < 4; ++rg)
          orow[(size_t)rg * 3136 + pp] = acc[i][j][rg];
      }
    }
  }
}

extern "C" void kernel_launch(void* const* d_in, const int* in_sizes, int n_in,
                              void* d_out, int out_size, void* d_ws, size_t ws_size,
                              hipStream_t stream) {
  const float* x      = (const float*)d_in[0];   // (32,256,56,56)
  const float* att_w  = (const float*)d_in[1];   // (4,256)
  const float* weight = (const float*)d_in[2];   // (4,256,256,3,3)
  float* out = (float*)d_out;                    // (32,256,56,56)

  char* ws = (char*)d_ws;
  float* pooled        = (float*)ws;                                // 32 KB (sums)
  float* att           = (float*)(ws + 32768);                      // 512 B
  unsigned short* agg  = (unsigned short*)(ws + 65536);             // 37,748,736 B
  unsigned short* xpad = (unsigned short*)(ws + 65536 + 37748736);  // 55,115,776 B

  zero_pooled_kernel<<<32, 256, 0, stream>>>(pooled);
  prep_kernel<<<6272, 256, 0, stream>>>(x, xpad, pooled);
  border_kernel<<<dim3(32, 4), 256, 0, stream>>>(xpad);
  att_kernel<<<1, 128, 0, stream>>>(pooled, att_w, att);
  agg_kernel<<<256, 256, 0, stream>>>(weight, att, agg);
  conv_kernel<<<1600, 256, 0, stream>>>(xpad, agg, out);
}

// Round 4
// 325.367 us; speedup vs baseline: 1.6404x; 1.6404x over previous
//
#include <hip/hip_runtime.h>

typedef __attribute__((ext_vector_type(8))) short short8;
typedef __attribute__((ext_vector_type(4))) float floatx4;

__device__ __forceinline__ unsigned short bf16_rne(float f) {
  unsigned int u = __builtin_bit_cast(unsigned int, f);
  u += 0x7fffu + ((u >> 16) & 1u);
  return (unsigned short)(u >> 16);
}

__device__ __forceinline__ void glds16(const void* g, void* l) {
  __builtin_amdgcn_global_load_lds((const __attribute__((address_space(1))) void*)g,
                                   (__attribute__((address_space(3))) void*)l, 16, 0, 0);
}

// xpad layout: [b][kc 8][pos 3364 = 58*58][cil 32] bf16  (chunk-major, glds-contiguous)
// agg  layout: [b][kc 8][rs 9][co 256][cil 32] bf16      (A-slab glds-contiguous)

// ---------------- zero pooledk (32x4 floats of pre-dot attention sums) ----------------
__global__ void zero_pk_kernel(float* __restrict__ pk) {
  pk[threadIdx.x] = 0.f;
}

// ---------------- prep: transpose+cast x into xpad; fused att-dot partial sums ----------------
__global__ __launch_bounds__(256) void prep_kernel(const float* __restrict__ x,
                                                   const float* __restrict__ att_w,
                                                   unsigned short* __restrict__ xpad,
                                                   float* __restrict__ pooledk) {
  const int bid = blockIdx.x;          // 32 b x 4 cig x 49 spc
  const int b   = bid / 196;
  const int rem = bid - b * 196;
  const int cig = rem / 49;
  const int spc = rem - cig * 49;
  const int t  = threadIdx.x;
  const int cs = t >> 6, sl = t & 63;
  const int sp0 = spc * 64;

  __shared__ unsigned short T2[64 * 72];   // [sp 64][ci 64], pitch 72 ush (b128-aligned, bank-balanced)
  __shared__ float red[4][4];

  // 16 coalesced row loads (256B per instr), kept in registers
  const float* xrow = x + (size_t)(b * 256 + cig * 64 + cs * 16) * 3136 + sp0 + sl;
  float v[16];
  #pragma unroll
  for (int i = 0; i < 16; ++i) v[i] = xrow[(size_t)i * 3136];

  // attention partial: butterfly row-sum, then dot with att_w (4 experts)
  float acc0 = 0.f, acc1 = 0.f, acc2 = 0.f, acc3 = 0.f;
  #pragma unroll
  for (int i = 0; i < 16; ++i) {
    float s = v[i];
    #pragma unroll
    for (int o = 32; o > 0; o >>= 1) s += __shfl_xor(s, o, 64);
    const int ci = cig * 64 + cs * 16 + i;
    acc0 += s * att_w[0 * 256 + ci];
    acc1 += s * att_w[1 * 256 + ci];
    acc2 += s * att_w[2 * 256 + ci];
    acc3 += s * att_w[3 * 256 + ci];
  }
  if (sl == 0) { red[cs][0] = acc0; red[cs][1] = acc1; red[cs][2] = acc2; red[cs][3] = acc3; }

  // transpose: pack 16 consecutive-ci bf16 into two b128 LDS writes
  short8 w0, w1;
  #pragma unroll
  for (int i = 0; i < 8; ++i) w0[i] = (short)bf16_rne(v[i]);
  #pragma unroll
  for (int i = 0; i < 8; ++i) w1[i] = (short)bf16_rne(v[8 + i]);
  *(short8*)(T2 + sl * 72 + cs * 16) = w0;
  *(short8*)(T2 + sl * 72 + cs * 16 + 8) = w1;
  __syncthreads();

  if (t < 4) {
    float s = red[0][t] + red[1][t] + red[2][t] + red[3][t];
    atomicAdd(&pooledk[b * 4 + t], s);      // 4 atomics per block total
  }

  // xpad write: two b128 LDS reads + two 16B stores (4-lane groups cover full 64B lines)
  unsigned short* xb = xpad + (size_t)b * (8 * 3364 * 32);
  #pragma unroll
  for (int it = 0; it < 2; ++it) {
    const int c = it * 256 + t;              // 0..511: (spl, oc8)
    const int spl = c >> 3, oc8 = c & 7;
    const int cg8 = cig * 8 + oc8;
    const int kc = cg8 >> 2, o2 = cg8 & 3;
    const int spg = sp0 + spl;
    const int h = spg / 56, wc = spg - h * 56;
    const int pos = (h + 1) * 58 + (wc + 1);
    const short8 vv = *(const short8*)(T2 + spl * 72 + oc8 * 8);
    *(short8*)(xb + (size_t)kc * (3364 * 32) + pos * 32 + o2 * 8) = vv;
  }
}

// ---------------- zero the padding border of xpad ----------------
__global__ __launch_bounds__(256) void border_kernel(unsigned short* __restrict__ xpad) {
  const int b = blockIdx.x, quarter = blockIdx.y, t = threadIdx.x;
  const short8 z = {0, 0, 0, 0, 0, 0, 0, 0};
  unsigned short* xb = xpad + (size_t)b * (8 * 3364 * 32);
  for (int it = 0; it < 8; ++it) {
    const int idx = it * 256 + t;                 // 57 pos x 8 kc x 4 chunks = 1824
    if (idx >= 1824) break;
    const int s8 = idx & 3, kc = (idx >> 2) & 7, j = idx >> 5;
    const int pi = quarter * 57 + j;
    int h2, w2;
    if (pi < 58)       { h2 = 0;  w2 = pi; }
    else if (pi < 116) { h2 = 57; w2 = pi - 58; }
    else { const int k = pi - 116; h2 = 1 + (k >> 1); w2 = (k & 1) * 57; }
    *(short8*)(xb + (size_t)kc * (3364 * 32) + (h2 * 58 + w2) * 32 + s8 * 8) = z;
  }
}

// ---------------- att[b][k] = sigmoid(pooledk / 3136) ----------------
__global__ void att_kernel(const float* __restrict__ pooledk,
                           float* __restrict__ att) {
  const int t = threadIdx.x;               // 128
  const float z = pooledk[t] * (1.f / 3136.f);
  att[t] = 1.f / (1.f + expf(-z));
}

// ---------------- agg: one block per co; coalesced weight staging; new layout out ----------------
__global__ __launch_bounds__(256) void agg_kernel(const float* __restrict__ w,
                                                  const float* __restrict__ att,
                                                  unsigned short* __restrict__ agg) {
  const int co = blockIdx.x;
  const int t = threadIdx.x;
  __shared__ float W[4][2304];
  __shared__ float attl[128];
  if (t < 128) attl[t] = att[t];
  #pragma unroll
  for (int e = 0; e < 4; ++e) {
    const float* src = w + (size_t)(e * 256 + co) * 2304;
    #pragma unroll
    for (int j = 0; j < 9; ++j) W[e][j * 256 + t] = src[j * 256 + t];
  }
  __syncthreads();

  int widx[9], off9[9];
  #pragma unroll
  for (int j = 0; j < 9; ++j) {
    const int task = j * 256 + t;            // (kc,rs,cil)
    const int cil = task & 31, pair = task >> 5;
    const int kc = pair / 9, rs = pair - kc * 9;
    widx[j] = (kc * 32 + cil) * 9 + rs;      // w index: ci*9 + rs
    off9[j] = pair * 8192 + co * 32 + cil;   // agg offset within b
  }
  for (int b = 0; b < 32; ++b) {
    const float a0 = attl[b * 4 + 0], a1 = attl[b * 4 + 1];
    const float a2 = attl[b * 4 + 2], a3 = attl[b * 4 + 3];
    unsigned short* dst = agg + (size_t)b * 589824;
    #pragma unroll
    for (int j = 0; j < 9; ++j) {
      const int wi = widx[j];
      float s = a0 * W[0][wi] + a1 * W[1][wi] + a2 * W[2][wi] + a3 * W[3][wi];
      dst[off9[j]] = bf16_rne(s);
    }
  }
}

// ---------------- conv: implicit GEMM, 128co x 128p, 3-rs groups, 48 MFMA/barrier window ----------------
__global__ __launch_bounds__(256) void conv_kernel(const unsigned short* __restrict__ xpad,
                                                   const unsigned short* __restrict__ aggw,
                                                   float* __restrict__ out) {
  __shared__ unsigned short Bsm[348 * 32];       // 22272 B: [local pos][cil 32]
  __shared__ unsigned short Asm[3 * 128 * 32];   // 24576 B: [rsl][co 128][k 32]

  const int t  = threadIdx.x;
  const int bx = blockIdx.x;
  const int p_t  = bx % 25;
  const int co_t = (bx / 25) & 1;
  const int b    = bx / 50;
  const int p0   = p_t * 128;
  const int oh_min = p0 / 56;

  const unsigned short* xb  = xpad + (size_t)b * (8 * 3364 * 32);
  const unsigned short* awb = aggw + (size_t)b * 589824 + co_t * 4096;

  const int lane = t & 63;
  const int wv = t >> 6;
  const int wm = wv >> 1;                   // co half
  const int wn = wv & 1;                    // p half
  const int m16 = lane & 15;
  const int q = lane >> 4;

  int aoff[4], boff[4];
  #pragma unroll
  for (int i = 0; i < 4; ++i)
    aoff[i] = (wm * 64 + i * 16 + m16) * 32 + q * 8;
  #pragma unroll
  for (int j = 0; j < 4; ++j) {
    const int pf = p0 + wn * 64 + j * 16 + m16;
    const int oh = pf / 56;
    const int ow = pf - oh * 56;
    boff[j] = ((oh - oh_min) * 58 + ow) * 32 + q * 8;
  }

  floatx4 acc[4][4];
  #pragma unroll
  for (int i = 0; i < 4; ++i)
    #pragma unroll
    for (int j = 0; j < 4; ++j)
      acc[i][j] = (floatx4){0.f, 0.f, 0.f, 0.f};

  for (int kc = 0; kc < 8; ++kc) {
    const unsigned short* xkc = xb + (size_t)kc * (3364 * 32);
    // ---- stage B x-tile: 348 pos x 32 ci, contiguous glds ----
    #pragma unroll
    for (int i = 0; i < 6; ++i) {
      const int c = i * 256 + t;
      if (c < 1392) {
        const int pos = c >> 2, sub = c & 3;
        const int prow = pos / 58;
        const int pcol = pos - prow * 58;
        int ih2 = oh_min + prow; if (ih2 > 57) ih2 = 57;   // clamp (dup rows unused)
        glds16(xkc + ((size_t)(ih2 * 58 + pcol) * 32 + sub * 8), (void*)(Bsm + c * 8));
      }
    }
    #pragma unroll
    for (int g = 0; g < 3; ++g) {
      // ---- stage A: 3 rs-slices (r = g, s = 0..2), contiguous per slice ----
      #pragma unroll
      for (int i = 0; i < 6; ++i) {
        const int c = i * 256 + t;
        const int rsl = c >> 9;
        const int w5 = c & 511;
        glds16(awb + (size_t)(kc * 9 + g * 3 + rsl) * 8192 + w5 * 8, (void*)(Asm + c * 8));
      }
      __syncthreads();   // drains glds + barrier

      #pragma unroll
      for (int rsl = 0; rsl < 3; ++rsl) {
        const int d = (g * 58 + rsl) * 32;     // shift: r = g, s = rsl
        short8 af[4], bf[4];
        #pragma unroll
        for (int i = 0; i < 4; ++i)
          af[i] = *(const short8*)(Asm + rsl * 4096 + aoff[i]);
        #pragma unroll
        for (int j = 0; j < 4; ++j)
          bf[j] = *(const short8*)(Bsm + boff[j] + d);
        #pragma unroll
        for (int i = 0; i < 4; ++i)
          #pragma unroll
          for (int j = 0; j < 4; ++j)
            acc[i][j] = __builtin_amdgcn_mfma_f32_16x16x32_bf16(af[i], bf[j], acc[i][j], 0, 0, 0);
      }
      __syncthreads();   // protect Asm (and Bsm at kc rollover)
    }
  }

  // ---- epilogue: D col = lane&15 (p), row = q*4+reg (co) ----
  #pragma unroll
  for (int i = 0; i < 4; ++i) {
    const int co = co_t * 128 + wm * 64 + i * 16 + q * 4;
    float* orow = out + (size_t)(b * 256 + co) * 3136;
    #pragma unroll
    for (int j = 0; j < 4; ++j) {
      const int pp = p0 + wn * 64 + j * 16 + m16;
      if (pp < 3136) {
        #pragma unroll
        for (int rg = 0; rg < 4; ++rg)
          orow[(size_t)rg * 3136 + pp] = acc[i][j][rg];
      }
    }
  }
}

extern "C" void kernel_launch(void* const* d_in, const int* in_sizes, int n_in,
                              void* d_out, int out_size, void* d_ws, size_t ws_size,
                              hipStream_t stream) {
  const float* x      = (const float*)d_in[0];   // (32,256,56,56)
  const float* att_w  = (const float*)d_in[1];   // (4,256)
  const float* weight = (const float*)d_in[2];   // (4,256,256,3,3)
  float* out = (float*)d_out;                    // (32,256,56,56)

  char* ws = (char*)d_ws;
  float* pooledk       = (float*)ws;                                // 512 B (pre-dot sums)
  float* att           = (float*)(ws + 32768);                      // 512 B
  unsigned short* agg  = (unsigned short*)(ws + 65536);             // 37,748,736 B
  unsigned short* xpad = (unsigned short*)(ws + 65536 + 37748736);  // 55,115,776 B

  zero_pk_kernel<<<1, 128, 0, stream>>>(pooledk);
  prep_kernel<<<6272, 256, 0, stream>>>(x, att_w, xpad, pooledk);
  border_kernel<<<dim3(32, 4), 256, 0, stream>>>(xpad);
  att_kernel<<<1, 128, 0, stream>>>(pooledk, att);
  agg_kernel<<<256, 256, 0, stream>>>(weight, att, agg);
  conv_kernel<<<1600, 256, 0, stream>>>(xpad, agg, out);
}